// Round 3
// baseline (204.323 us; speedup 1.0000x reference)
//
#include <hip/hip_runtime.h>

#define LOG2E 1.4426950408889634f

// Problem constants
constexpr int Bb = 4, LQ = 512, LK = 512, QS = 512, H = 256, DV = 512;
constexpr int M = Bb * LQ;   // 2048 rows for both projections

// ---------------------------------------------------------------------------
// Kernel A: fused Q/K projection + exp2 epilogue, TRANSPOSED output.
//   EqT[n][m] = exp2( clamp( scale*(A[m]·W[n] + bias[n]), ±60 ) )
// Dot-product formulation: both tiles staged ROW-MAJOR (contiguous float4
// writes -> conflict-free), pitch 36 (144B rows, 16B aligned). Frag index
// m = tx + 16i spreads b128 reads over all 8 quad-banks (2-way, free).
// 32x32 tiles, grid (64, 8, 2) = 1024 blocks -> 4 blocks/CU, 16 waves/CU.
// ---------------------------------------------------------------------------
__global__ __launch_bounds__(256) void proj2_kernel(
    const float* __restrict__ Aq, const float* __restrict__ Ak,
    const float* __restrict__ Wq, const float* __restrict__ Wk,
    const float* __restrict__ Bq, const float* __restrict__ Bk,
    float* __restrict__ EqT, float* __restrict__ EkT, float scale)
{
    const int K = QS;
    const float* A    = blockIdx.z ? Ak : Aq;
    const float* W    = blockIdx.z ? Wk : Wq;
    const float* bias = blockIdx.z ? Bk : Bq;
    float*       C    = blockIdx.z ? EkT : EqT;   // [H][M] transposed

    __shared__ float As[32][36];   // [m][k], pitch 36
    __shared__ float Ws[32][36];   // [n][k], pitch 36
    const int bm = blockIdx.x * 32;
    const int bn = blockIdx.y * 32;
    const int tid = threadIdx.x;
    const int tx = tid & 15;       // m: tx, tx+16
    const int ty = tid >> 4;       // n: ty, ty+16

    float4 accv[2][2] = {};        // component-wise partial sums (k mod 4)

    const int r = tid >> 3;            // 0..31 staging row
    const int c = (tid & 7) * 4;       // 0..28 staging col

    for (int k0 = 0; k0 < K; k0 += 32) {
        *(float4*)&As[r][c] = *(const float4*)(A + (size_t)(bm + r) * K + k0 + c);
        *(float4*)&Ws[r][c] = *(const float4*)(W + (size_t)(bn + r) * K + k0 + c);
        __syncthreads();
#pragma unroll
        for (int kk = 0; kk < 8; ++kk) {
            const float4 a0 = *(const float4*)&As[tx][kk * 4];
            const float4 a1 = *(const float4*)&As[tx + 16][kk * 4];
            const float4 w0 = *(const float4*)&Ws[ty][kk * 4];
            const float4 w1 = *(const float4*)&Ws[ty + 16][kk * 4];
            accv[0][0].x = fmaf(a0.x, w0.x, accv[0][0].x);
            accv[0][0].y = fmaf(a0.y, w0.y, accv[0][0].y);
            accv[0][0].z = fmaf(a0.z, w0.z, accv[0][0].z);
            accv[0][0].w = fmaf(a0.w, w0.w, accv[0][0].w);
            accv[0][1].x = fmaf(a0.x, w1.x, accv[0][1].x);
            accv[0][1].y = fmaf(a0.y, w1.y, accv[0][1].y);
            accv[0][1].z = fmaf(a0.z, w1.z, accv[0][1].z);
            accv[0][1].w = fmaf(a0.w, w1.w, accv[0][1].w);
            accv[1][0].x = fmaf(a1.x, w0.x, accv[1][0].x);
            accv[1][0].y = fmaf(a1.y, w0.y, accv[1][0].y);
            accv[1][0].z = fmaf(a1.z, w0.z, accv[1][0].z);
            accv[1][0].w = fmaf(a1.w, w0.w, accv[1][0].w);
            accv[1][1].x = fmaf(a1.x, w1.x, accv[1][1].x);
            accv[1][1].y = fmaf(a1.y, w1.y, accv[1][1].y);
            accv[1][1].z = fmaf(a1.z, w1.z, accv[1][1].z);
            accv[1][1].w = fmaf(a1.w, w1.w, accv[1][1].w);
        }
        __syncthreads();
    }
    // Epilogue: horizontal sum, bias, scale, clamp, exp2, transposed store.
#pragma unroll
    for (int j = 0; j < 2; ++j) {
        int n = bn + ty + 16 * j;
        float bs = bias[n];
#pragma unroll
        for (int i = 0; i < 2; ++i) {
            float4 s4 = accv[i][j];
            float s = (s4.x + s4.y) + (s4.z + s4.w);
            float v = scale * (s + bs);
            v = fminf(fmaxf(v, -60.f), 60.f);
            C[(size_t)n * M + bm + tx + 16 * i] = __builtin_amdgcn_exp2f(v);
        }
    }
}

// ---------------------------------------------------------------------------
// Kernel B: scores (log2 domain, bv dropped).
//   s' = SW - sum_h Wv2[h] * rcp(1 + EqT[h][q]*EkT[h][k])
// 32q x 32k tiles, 2x2/thread, grid (16,16,B) = 1024 blocks -> 4 blocks/CU.
// Staging is contiguous row-major (conflict-free); frag reads are b64
// broadcast (Qs) / 16-distinct (Ks) — both free.
// ---------------------------------------------------------------------------
__global__ __launch_bounds__(256) void score_kernel(
    const float* __restrict__ EqT,   // [H][M] exp2 domain
    const float* __restrict__ EkT,   // [H][M]
    const float* __restrict__ wv,    // [H]
    float* __restrict__ Sc)          // [B*LQ, LK]
{
    __shared__ float Qs[32][32];
    __shared__ float Ks[32][32];
    __shared__ float Wv2[H];
    const int b  = blockIdx.z;
    const int qb = blockIdx.x * 32, kb = blockIdx.y * 32;
    const int tid = threadIdx.x;
    const int tx = tid & 15;       // k pair: kb + tx*2 + j
    const int ty = tid >> 4;       // q pair: qb + ty*2 + i

    Wv2[tid] = wv[tid] * (2.0f * LOG2E);   // blockDim == H == 256
    __syncthreads();

    float SW;
    {
        float4 s4 = {0.f, 0.f, 0.f, 0.f};
        for (int h = 0; h < H; h += 4) {
            float4 w4 = *(const float4*)&Wv2[h];
            s4.x += w4.x; s4.y += w4.y; s4.z += w4.z; s4.w += w4.w;
        }
        SW = 0.5f * ((s4.x + s4.y) + (s4.z + s4.w));
    }

    float acc[2][2] = {};
    const int mq = b * LQ + qb;
    const int mk = b * LK + kb;
    const int sr = tid >> 3;           // 0..31 staging row (h)
    const int sc = (tid & 7) * 4;      // 0..28 staging col (m)

    for (int h0 = 0; h0 < H; h0 += 32) {
        *(float4*)&Qs[sr][sc] = *(const float4*)(EqT + (size_t)(h0 + sr) * M + mq + sc);
        *(float4*)&Ks[sr][sc] = *(const float4*)(EkT + (size_t)(h0 + sr) * M + mk + sc);
        __syncthreads();
#pragma unroll
        for (int hh = 0; hh < 32; hh += 4) {
            float4 w4 = *(const float4*)&Wv2[h0 + hh];
#pragma unroll
            for (int u = 0; u < 4; ++u) {
                float w = u == 0 ? w4.x : (u == 1 ? w4.y : (u == 2 ? w4.z : w4.w));
                float2 q2 = *(const float2*)&Qs[hh + u][ty * 2];
                float2 k2 = *(const float2*)&Ks[hh + u][tx * 2];
                float t00 = fmaf(q2.x, k2.x, 1.0f);
                float t01 = fmaf(q2.x, k2.y, 1.0f);
                float t10 = fmaf(q2.y, k2.x, 1.0f);
                float t11 = fmaf(q2.y, k2.y, 1.0f);
                acc[0][0] = fmaf(w, __builtin_amdgcn_rcpf(t00), acc[0][0]);
                acc[0][1] = fmaf(w, __builtin_amdgcn_rcpf(t01), acc[0][1]);
                acc[1][0] = fmaf(w, __builtin_amdgcn_rcpf(t10), acc[1][0]);
                acc[1][1] = fmaf(w, __builtin_amdgcn_rcpf(t11), acc[1][1]);
            }
        }
        __syncthreads();
    }
#pragma unroll
    for (int i = 0; i < 2; ++i) {
        int q = qb + ty * 2 + i;
        float2 o;
        o.x = SW - acc[i][0];
        o.y = SW - acc[i][1];
        *(float2*)(Sc + ((size_t)b * LQ + q) * LK + kb + tx * 2) = o;
    }
}

// ---------------------------------------------------------------------------
// Kernel C: row softmax in-place on Sc (log2 domain -> plain exp2).
// One block (256 thr) per row of 512; 2 elements/thread.
// ---------------------------------------------------------------------------
__global__ __launch_bounds__(256) void softmax_kernel(float* __restrict__ Sc)
{
    const int row = blockIdx.x;
    float* s = Sc + (size_t)row * LK;
    const int tid = threadIdx.x;
    float2 v = *(float2*)(s + tid * 2);

    float m = fmaxf(v.x, v.y);
#pragma unroll
    for (int off = 32; off >= 1; off >>= 1)
        m = fmaxf(m, __shfl_xor(m, off, 64));
    __shared__ float redm[4];
    const int wid = tid >> 6, lane = tid & 63;
    if (lane == 0) redm[wid] = m;
    __syncthreads();
    m = fmaxf(fmaxf(redm[0], redm[1]), fmaxf(redm[2], redm[3]));

    float e0 = __builtin_amdgcn_exp2f(v.x - m);
    float e1 = __builtin_amdgcn_exp2f(v.y - m);
    float sum = e0 + e1;
#pragma unroll
    for (int off = 32; off >= 1; off >>= 1)
        sum += __shfl_xor(sum, off, 64);
    __shared__ float reds[4];
    if (lane == 0) reds[wid] = sum;
    __syncthreads();
    sum = (reds[0] + reds[1]) + (reds[2] + reds[3]);

    float rs = 1.0f / sum;
    float2 o; o.x = e0 * rs; o.y = e1 * rs;
    *(float2*)(s + tid * 2) = o;
}

// ---------------------------------------------------------------------------
// Kernel D: out = attn @ value.  O[q][n] = sum_k At[q][k] * V[k][n].
// 32x32 tiles, grid (16,16,B) = 1024 blocks -> 4 blocks/CU.
// At tile row-major [q][k] pitch 36 (144B rows, always 16B aligned);
// V tile natural [k][n] pitch 32.  a-reads b128 broadcast, v-reads b64 free.
// ---------------------------------------------------------------------------
__global__ __launch_bounds__(256) void av_kernel(
    const float* __restrict__ At,   // [B*LQ, LK] attention weights
    const float* __restrict__ V,    // [B, LK, DV]
    float* __restrict__ O)          // [B*LQ, DV]
{
    __shared__ float As[32][36];    // [q][k]
    __shared__ float Vs[32][32];    // [k][n]
    const int b  = blockIdx.z;
    const int qb = blockIdx.x * 32, nb = blockIdx.y * 32;
    const int tid = threadIdx.x;
    const int tx = tid & 15;        // n pair: nb + tx*2 + j
    const int ty = tid >> 4;        // q pair: qb + ty*2 + i
    float acc[2][2] = {};
    const float* Ab = At + ((size_t)b * LQ + qb) * LK;
    const float* Vb = V + (size_t)b * LK * DV;
    const int sr = tid >> 3;        // 0..31
    const int sc = (tid & 7) * 4;   // 0..28

    for (int k0 = 0; k0 < LK; k0 += 32) {
        *(float4*)&As[sr][sc] = *(const float4*)(Ab + (size_t)sr * LK + k0 + sc);
        *(float4*)&Vs[sr][sc] = *(const float4*)(Vb + (size_t)(k0 + sr) * DV + nb + sc);
        __syncthreads();
#pragma unroll
        for (int k4 = 0; k4 < 8; ++k4) {
            const float4 a0 = *(const float4*)&As[ty * 2 + 0][k4 * 4];
            const float4 a1 = *(const float4*)&As[ty * 2 + 1][k4 * 4];
            const float2 v0 = *(const float2*)&Vs[k4 * 4 + 0][tx * 2];
            const float2 v1 = *(const float2*)&Vs[k4 * 4 + 1][tx * 2];
            const float2 v2 = *(const float2*)&Vs[k4 * 4 + 2][tx * 2];
            const float2 v3 = *(const float2*)&Vs[k4 * 4 + 3][tx * 2];
            acc[0][0] = fmaf(a0.x, v0.x, acc[0][0]);
            acc[0][1] = fmaf(a0.x, v0.y, acc[0][1]);
            acc[1][0] = fmaf(a1.x, v0.x, acc[1][0]);
            acc[1][1] = fmaf(a1.x, v0.y, acc[1][1]);
            acc[0][0] = fmaf(a0.y, v1.x, acc[0][0]);
            acc[0][1] = fmaf(a0.y, v1.y, acc[0][1]);
            acc[1][0] = fmaf(a1.y, v1.x, acc[1][0]);
            acc[1][1] = fmaf(a1.y, v1.y, acc[1][1]);
            acc[0][0] = fmaf(a0.z, v2.x, acc[0][0]);
            acc[0][1] = fmaf(a0.z, v2.y, acc[0][1]);
            acc[1][0] = fmaf(a1.z, v2.x, acc[1][0]);
            acc[1][1] = fmaf(a1.z, v2.y, acc[1][1]);
            acc[0][0] = fmaf(a0.w, v3.x, acc[0][0]);
            acc[0][1] = fmaf(a0.w, v3.y, acc[0][1]);
            acc[1][0] = fmaf(a1.w, v3.x, acc[1][0]);
            acc[1][1] = fmaf(a1.w, v3.y, acc[1][1]);
        }
        __syncthreads();
    }
#pragma unroll
    for (int i = 0; i < 2; ++i) {
        int q = qb + ty * 2 + i;
        float2 o;
        o.x = acc[i][0];
        o.y = acc[i][1];
        *(float2*)(O + ((size_t)b * LQ + q) * DV + nb + tx * 2) = o;
    }
}

extern "C" void kernel_launch(void* const* d_in, const int* in_sizes, int n_in,
                              void* d_out, int out_size, void* d_ws, size_t ws_size,
                              hipStream_t stream) {
    const float* query = (const float*)d_in[0];
    const float* key   = (const float*)d_in[1];
    const float* value = (const float*)d_in[2];
    const float* wq    = (const float*)d_in[3];
    const float* bq    = (const float*)d_in[4];
    const float* wk    = (const float*)d_in[5];
    const float* bk    = (const float*)d_in[6];
    const float* wv    = (const float*)d_in[7];
    // d_in[8] = bv: row-constant -> softmax-invariant, dropped.
    float* out = (float*)d_out;

    float* EqT = (float*)d_ws;                     // [H][M] exp2-domain q
    float* EkT = EqT + (size_t)H * M;              // [H][M] exp2-domain k
    float* Sc  = EkT + (size_t)H * M;              // [M][LK] scores/attn

    const float c2 = 2.0f * LOG2E;

    proj2_kernel<<<dim3(M / 32, H / 32, 2), 256, 0, stream>>>(
        query, key, wq, wk, bq, bk, EqT, EkT, c2);
    score_kernel<<<dim3(LQ / 32, LK / 32, Bb), 256, 0, stream>>>(EqT, EkT, wv, Sc);
    softmax_kernel<<<Bb * LQ, 256, 0, stream>>>(Sc);
    av_kernel<<<dim3(LQ / 32, DV / 32, Bb), 256, 0, stream>>>(Sc, value, out);
}